// Round 2
// baseline (409.056 us; speedup 1.0000x reference)
//
#include <hip/hip_runtime.h>

#define BLOCK 256
#define C_DIM 10000
#define C4 (C_DIM / 4)
#define NIT ((C4 + BLOCK - 1) / BLOCK)   // 10
#define TAU 1.0f
#define CAP 2048                          // candidate buffer (8 KB LDS)

// Monotone bijection float -> uint32 (larger float => larger key)
__device__ __forceinline__ unsigned flip_key(float f) {
    unsigned u = __float_as_uint(f);
    return (u & 0x80000000u) ? ~u : (u | 0x80000000u);
}

__global__ void zero_out_kernel(float* out, int n) {
    int i = blockIdx.x * blockDim.x + threadIdx.x;
    if (i < n) out[i] = 0.f;
}

// Wave-aggregated histogram add: one atomic per unique digit per wave,
// instead of 64-way same-address serialization on clustered digits.
__device__ __forceinline__ void hist_add_agg(unsigned* hist, unsigned d, bool valid, int lane) {
    bool done = !valid;
    for (;;) {
        unsigned long long b = __ballot(!done);
        if (!b) break;                                  // wave-uniform exit
        int src = (int)(__ffsll((long long)b) - 1);
        unsigned dl = (unsigned)__shfl((int)d, src);
        bool match = (!done) && (d == dl);
        unsigned long long mb = __ballot(match);
        if (match) {
            done = true;
            if (lane == src) atomicAdd(&hist[dl], (unsigned)__popcll(mb));
        }
    }
}

// Wave 0 (tid<64): suffix-scan 256 bins (4/lane), pick bin containing the
// kr-th largest; update prefix / kr / selected-bin count.
__device__ __forceinline__ void scan_pick(unsigned* hist, int shift, int tid,
                                          unsigned* shp, unsigned* shkr, unsigned* shcnt) {
    unsigned h0 = hist[4 * tid + 0], h1 = hist[4 * tid + 1];
    unsigned h2 = hist[4 * tid + 2], h3 = hist[4 * tid + 3];
    unsigned loc = h0 + h1 + h2 + h3;
    unsigned suf = loc;
    for (int off = 1; off < 64; off <<= 1) {
        unsigned o = __shfl_down(suf, off);
        if (tid + off < 64) suf += o;
    }
    unsigned sufex = suf - loc;            // sum over bins strictly above my 4
    unsigned kr = *shkr;
    unsigned s3 = sufex + h3;
    unsigned s2 = s3 + h2;
    unsigned s1 = s2 + h1;
    unsigned s0 = s1 + h0;
    int bsel = -1; unsigned newkr = 0, newcnt = 0;
    if      (s3 >= kr && s3 - h3 < kr) { bsel = 4 * tid + 3; newkr = kr - (s3 - h3); newcnt = h3; }
    else if (s2 >= kr && s2 - h2 < kr) { bsel = 4 * tid + 2; newkr = kr - (s2 - h2); newcnt = h2; }
    else if (s1 >= kr && s1 - h1 < kr) { bsel = 4 * tid + 1; newkr = kr - (s1 - h1); newcnt = h1; }
    else if (s0 >= kr && s0 - h0 < kr) { bsel = 4 * tid + 0; newkr = kr - (s0 - h0); newcnt = h0; }
    if (bsel >= 0) {
        *shp |= ((unsigned)bsel << shift);
        *shkr = newkr;
        *shcnt = newcnt;
    }
}

__global__ __launch_bounds__(BLOCK, 8) void topk_la_loss_kernel(
    const float* __restrict__ logit, const int* __restrict__ target,
    const float* __restrict__ lcn, const int* __restrict__ kpc,
    float* __restrict__ out, int B) {
    __shared__ unsigned hist[256];
    __shared__ __align__(16) unsigned cand[CAP];
    __shared__ float red_a[4], red_b[4];
    __shared__ unsigned sh_prefix, sh_kr, sh_cnt, sh_ncand;
    __shared__ float sh_M;

    const int row = blockIdx.x;
    const int tid = threadIdx.x;
    const int lane = tid & 63;
    const int wid = tid >> 6;
    const float* lrow = logit + (size_t)row * C_DIM;

    if (tid == 0) {
        int t = target[row];
        int k = kpc[t];
        if (k > C_DIM) k = C_DIM;
        sh_kr = (unsigned)k;
        sh_prefix = 0u;
        sh_cnt = (unsigned)C_DIM;
        sh_ncand = 0u;
    }
    hist[tid] = 0u;
    __syncthreads();

    // ---- Pass 1: max(adjusted) + top-8-bit aggregated histogram (no exp)
    float madj = -INFINITY;
    for (int it = 0; it < NIT; ++it) {
        int j4 = it * BLOCK + tid;
        bool valid = j4 < C4;
        unsigned k0 = 0, k1 = 0, k2 = 0, k3 = 0;
        if (valid) {
            float4 f = ((const float4*)lrow)[j4];
            float4 l = ((const float4*)lcn)[j4];
            madj = fmaxf(madj, fmaxf(fmaxf(f.x + TAU * l.x, f.y + TAU * l.y),
                                     fmaxf(f.z + TAU * l.z, f.w + TAU * l.w)));
            k0 = flip_key(f.x); k1 = flip_key(f.y);
            k2 = flip_key(f.z); k3 = flip_key(f.w);
        }
        hist_add_agg(hist, k0 >> 24, valid, lane);
        hist_add_agg(hist, k1 >> 24, valid, lane);
        hist_add_agg(hist, k2 >> 24, valid, lane);
        hist_add_agg(hist, k3 >> 24, valid, lane);
    }
    for (int off = 32; off; off >>= 1) madj = fmaxf(madj, __shfl_down(madj, off));
    if (lane == 0) red_a[wid] = madj;
    __syncthreads();

    if (tid == 0) sh_M = fmaxf(fmaxf(red_a[0], red_a[1]), fmaxf(red_a[2], red_a[3]));
    if (tid < 64) scan_pick(hist, 24, tid, &sh_prefix, &sh_kr, &sh_cnt);
    __syncthreads();

    const float M = sh_M;

    // ---- Rare fallback: refine prefix with more global histogram passes
    int p = 0;
    while (sh_cnt > CAP && p < 3) {
        ++p;
        const int shift = 24 - 8 * p;
        const unsigned pmask = 0xFFFFFFFFu << (shift + 8);
        const unsigned pref = sh_prefix;
        hist[tid] = 0u;
        __syncthreads();
        for (int it = 0; it < NIT; ++it) {
            int j4 = it * BLOCK + tid;
            bool valid = j4 < C4;
            unsigned k0 = 0, k1 = 0, k2 = 0, k3 = 0;
            if (valid) {
                float4 f = ((const float4*)lrow)[j4];
                k0 = flip_key(f.x); k1 = flip_key(f.y);
                k2 = flip_key(f.z); k3 = flip_key(f.w);
            }
            hist_add_agg(hist, (k0 >> shift) & 0xFFu, valid && ((k0 & pmask) == pref), lane);
            hist_add_agg(hist, (k1 >> shift) & 0xFFu, valid && ((k1 & pmask) == pref), lane);
            hist_add_agg(hist, (k2 >> shift) & 0xFFu, valid && ((k2 & pmask) == pref), lane);
            hist_add_agg(hist, (k3 >> shift) & 0xFFu, valid && ((k3 & pmask) == pref), lane);
        }
        __syncthreads();
        if (tid < 64) scan_pick(hist, shift, tid, &sh_prefix, &sh_kr, &sh_cnt);
        __syncthreads();
    }

    // ---- Compact candidates matching the prefix, finish select in LDS
    if (p < 3) {
        const unsigned cmask = 0xFFFFFFFFu << (24 - 8 * p);
        const unsigned pref = sh_prefix;
        for (int it = 0; it < NIT; ++it) {
            int j4 = it * BLOCK + tid;
            if (j4 < C4) {
                float4 f = ((const float4*)lrow)[j4];
                unsigned kk;
                kk = flip_key(f.x); if ((kk & cmask) == pref) cand[atomicAdd(&sh_ncand, 1u)] = kk;
                kk = flip_key(f.y); if ((kk & cmask) == pref) cand[atomicAdd(&sh_ncand, 1u)] = kk;
                kk = flip_key(f.z); if ((kk & cmask) == pref) cand[atomicAdd(&sh_ncand, 1u)] = kk;
                kk = flip_key(f.w); if ((kk & cmask) == pref) cand[atomicAdd(&sh_ncand, 1u)] = kk;
            }
        }
        __syncthreads();
        const int ncand = (int)sh_ncand;

        for (int q = p + 1; q < 4; ++q) {
            const unsigned pref2 = sh_prefix;
            const unsigned cc = sh_cnt;
            const unsigned qmask = 0xFFFFFFFFu << (32 - 8 * q);
            const int shift = 24 - 8 * q;
            if (cc == 1u) {
                __syncthreads();   // pref2 read before the single-writer update
                for (int i = tid; i < ncand; i += BLOCK) {
                    unsigned kk = cand[i];
                    if ((kk & qmask) == pref2) sh_prefix = kk;   // exactly one match
                }
                __syncthreads();
                break;
            }
            hist[tid] = 0u;
            __syncthreads();
            for (int i = tid; i < ncand; i += BLOCK) {
                unsigned kk = cand[i];
                if ((kk & qmask) == pref2) atomicAdd(&hist[(kk >> shift) & 0xFFu], 1u);
            }
            __syncthreads();
            if (tid < 64) scan_pick(hist, shift, tid, &sh_prefix, &sh_kr, &sh_cnt);
            __syncthreads();
        }
    }
    const unsigned tkey = sh_prefix;   // exact key of k-th largest logit

    // ---- Pass 3: Z = sum exp(adj - M) and masked sum in one sweep
    float z = 0.f, sm = 0.f;
    for (int it = 0; it < NIT; ++it) {
        int j4 = it * BLOCK + tid;
        if (j4 < C4) {
            float4 f = ((const float4*)lrow)[j4];
            float4 l = ((const float4*)lcn)[j4];
            float e;
            e = __expf(f.x + TAU * l.x - M); z += e; if (flip_key(f.x) >= tkey) sm += e;
            e = __expf(f.y + TAU * l.y - M); z += e; if (flip_key(f.y) >= tkey) sm += e;
            e = __expf(f.z + TAU * l.z - M); z += e; if (flip_key(f.z) >= tkey) sm += e;
            e = __expf(f.w + TAU * l.w - M); z += e; if (flip_key(f.w) >= tkey) sm += e;
        }
    }
    for (int off = 32; off; off >>= 1) {
        z  += __shfl_down(z, off);
        sm += __shfl_down(sm, off);
    }
    if (lane == 0) { red_a[wid] = z; red_b[wid] = sm; }
    __syncthreads();

    if (tid == 0) {
        float Z = red_a[0] + red_a[1] + red_a[2] + red_a[3];
        float S = red_b[0] + red_b[1] + red_b[2] + red_b[3];
        int t = target[row];
        float logit_t = lrow[t];
        float adj_t = logit_t + TAU * lcn[t];
        float lpt = adj_t - M - __logf(Z);           // log_p_adj[target]
        unsigned key_t = flip_key(logit_t);
        float p_num = ((key_t >= tkey) ? __expf(lpt) : 0.f) + 1e-6f;
        float Smask = S / Z + (float)C_DIM * 1e-6f;
        float loss = 0.5f * (-lpt + __logf(Smask) - __logf(p_num));
        atomicAdd(out, loss / (float)B);
    }
}

extern "C" void kernel_launch(void* const* d_in, const int* in_sizes, int n_in,
                              void* d_out, int out_size, void* d_ws, size_t ws_size,
                              hipStream_t stream) {
    const float* logit  = (const float*)d_in[0];
    const int*   target = (const int*)d_in[1];
    const float* lcn    = (const float*)d_in[2];
    const int*   kpc    = (const int*)d_in[3];
    float* out = (float*)d_out;
    const int B = in_sizes[1];   // target is [B]

    zero_out_kernel<<<1, 64, 0, stream>>>(out, out_size);
    topk_la_loss_kernel<<<B, BLOCK, 0, stream>>>(logit, target, lcn, kpc, out, B);
}

// Round 3
// 268.048 us; speedup vs baseline: 1.5261x; 1.5261x over previous
//
#include <hip/hip_runtime.h>

#define BLOCK 256
#define C_DIM 10000
#define C4 (C_DIM / 4)
#define NIT ((C4 + BLOCK - 1) / BLOCK)   // 10
#define TAU 1.0f
#define CAP 2048
#define PIV_HI 2.0f
#define PIV_LO 1.0f

// Monotone bijection float -> uint32 (larger float => larger key)
__device__ __forceinline__ unsigned flip_key(float f) {
    unsigned u = __float_as_uint(f);
    return (u & 0x80000000u) ? ~u : (u | 0x80000000u);
}
__device__ __forceinline__ float unflip_key(unsigned k) {
    unsigned u = (k & 0x80000000u) ? (k & 0x7fffffffu) : ~k;
    return __uint_as_float(u);
}

__global__ void zero_out_kernel(float* out, int n) {
    int i = blockIdx.x * blockDim.x + threadIdx.x;
    if (i < n) out[i] = 0.f;
}

// Wave 0 (tid<64): suffix-scan 256 bins (4/lane), pick the bin containing the
// kr-th largest; update prefix / kr / selected-bin count. Exactly one lane writes.
__device__ __forceinline__ void scan_pick(unsigned* hist, int shift, int tid,
                                          unsigned* shp, unsigned* shkr, unsigned* shcnt) {
    unsigned h0 = hist[4 * tid + 0], h1 = hist[4 * tid + 1];
    unsigned h2 = hist[4 * tid + 2], h3 = hist[4 * tid + 3];
    unsigned loc = h0 + h1 + h2 + h3;
    unsigned suf = loc;
    for (int off = 1; off < 64; off <<= 1) {
        unsigned o = __shfl_down(suf, off);
        if (tid + off < 64) suf += o;
    }
    unsigned sufex = suf - loc;            // sum over bins strictly above my 4
    unsigned kr = *shkr;
    unsigned s3 = sufex + h3;
    unsigned s2 = s3 + h2;
    unsigned s1 = s2 + h1;
    unsigned s0 = s1 + h0;
    int bsel = -1; unsigned newkr = 0, newcnt = 0;
    if      (s3 >= kr && s3 - h3 < kr) { bsel = 4 * tid + 3; newkr = kr - (s3 - h3); newcnt = h3; }
    else if (s2 >= kr && s2 - h2 < kr) { bsel = 4 * tid + 2; newkr = kr - (s2 - h2); newcnt = h2; }
    else if (s1 >= kr && s1 - h1 < kr) { bsel = 4 * tid + 1; newkr = kr - (s1 - h1); newcnt = h1; }
    else if (s0 >= kr && s0 - h0 < kr) { bsel = 4 * tid + 0; newkr = kr - (s0 - h0); newcnt = h0; }
    if (bsel >= 0) {
        *shp |= ((unsigned)bsel << shift);
        *shkr = newkr;
        *shcnt = newcnt;
    }
}

__global__ __launch_bounds__(BLOCK, 8) void topk_la_loss_kernel(
    const float* __restrict__ logit, const int* __restrict__ target,
    const float* __restrict__ lcn, const int* __restrict__ kpc,
    float* __restrict__ out, int B) {
    __shared__ unsigned hist[256];
    __shared__ unsigned candk[CAP];          // raw float bits (positive vals)
    __shared__ unsigned short candi[CAP];    // element index (for lcn fetch)
    __shared__ float red_a[4], red_b[4];
    __shared__ unsigned sh_nc, sh_prefix, sh_kr, sh_cnt;
    __shared__ int sh_path, sh_k;
    __shared__ float sh_thresh, sh_madj;

    const int row = blockIdx.x;
    const int tid = threadIdx.x;
    const int lane = tid & 63;
    const int wid = tid >> 6;
    const float* lrow = logit + (size_t)row * C_DIM;

    if (tid == 0) {
        int t = target[row];
        int k = kpc[t];
        if (k > C_DIM) k = C_DIM;
        sh_k = k;
        sh_nc = 0u;
    }
    __syncthreads();

    // ---- Fused sweep: z = sum exp(adj) (no max-sub; |madj|>80 guard),
    //      max(adj), compact logit >= PIV_HI into LDS.
    float z = 0.f, madj = -INFINITY;
    for (int it = 0; it < NIT; ++it) {
        int j4 = it * BLOCK + tid;
        if (j4 < C4) {
            float4 f = ((const float4*)lrow)[j4];
            float4 l = ((const float4*)lcn)[j4];
            float a0 = f.x + TAU * l.x, a1 = f.y + TAU * l.y;
            float a2 = f.z + TAU * l.z, a3 = f.w + TAU * l.w;
            z += __expf(a0) + __expf(a1) + __expf(a2) + __expf(a3);
            madj = fmaxf(madj, fmaxf(fmaxf(a0, a1), fmaxf(a2, a3)));
            int j = 4 * j4;
            if (f.x >= PIV_HI) { unsigned i = atomicAdd(&sh_nc, 1u); if (i < CAP) { candk[i] = __float_as_uint(f.x); candi[i] = (unsigned short)(j + 0); } }
            if (f.y >= PIV_HI) { unsigned i = atomicAdd(&sh_nc, 1u); if (i < CAP) { candk[i] = __float_as_uint(f.y); candi[i] = (unsigned short)(j + 1); } }
            if (f.z >= PIV_HI) { unsigned i = atomicAdd(&sh_nc, 1u); if (i < CAP) { candk[i] = __float_as_uint(f.z); candi[i] = (unsigned short)(j + 2); } }
            if (f.w >= PIV_HI) { unsigned i = atomicAdd(&sh_nc, 1u); if (i < CAP) { candk[i] = __float_as_uint(f.w); candi[i] = (unsigned short)(j + 3); } }
        }
    }
    for (int off = 32; off; off >>= 1) madj = fmaxf(madj, __shfl_down(madj, off));
    if (lane == 0) red_a[wid] = madj;
    __syncthreads();

    if (tid == 0) {
        sh_madj = fmaxf(fmaxf(red_a[0], red_a[1]), fmaxf(red_a[2], red_a[3]));
        unsigned n = sh_nc;
        unsigned k = (unsigned)sh_k;
        sh_path = (n >= k && n <= CAP) ? 0 : ((n < k) ? 1 : 2);
        sh_kr = k;
        sh_prefix = 0u;
        sh_cnt = n;
    }
    __syncthreads();

    // ---- Rare: too few candidates at PIV_HI -> recompact at PIV_LO
    if (sh_path == 1) {
        if (tid == 0) sh_nc = 0u;
        __syncthreads();
        for (int it = 0; it < NIT; ++it) {
            int j4 = it * BLOCK + tid;
            if (j4 < C4) {
                float4 f = ((const float4*)lrow)[j4];
                int j = 4 * j4;
                if (f.x >= PIV_LO) { unsigned i = atomicAdd(&sh_nc, 1u); if (i < CAP) { candk[i] = __float_as_uint(f.x); candi[i] = (unsigned short)(j + 0); } }
                if (f.y >= PIV_LO) { unsigned i = atomicAdd(&sh_nc, 1u); if (i < CAP) { candk[i] = __float_as_uint(f.y); candi[i] = (unsigned short)(j + 1); } }
                if (f.z >= PIV_LO) { unsigned i = atomicAdd(&sh_nc, 1u); if (i < CAP) { candk[i] = __float_as_uint(f.z); candi[i] = (unsigned short)(j + 2); } }
                if (f.w >= PIV_LO) { unsigned i = atomicAdd(&sh_nc, 1u); if (i < CAP) { candk[i] = __float_as_uint(f.w); candi[i] = (unsigned short)(j + 3); } }
            }
        }
        __syncthreads();
        if (tid == 0) {
            unsigned n = sh_nc;
            unsigned k = (unsigned)sh_k;
            sh_path = (n >= k && n <= CAP) ? 0 : 2;
            sh_kr = k;
            sh_prefix = 0u;
            sh_cnt = n;
        }
        __syncthreads();
    }

    const int path = sh_path;
    const float madjB = sh_madj;

    if (path == 0) {
        // ---- Exact byte-radix select among nc LDS candidates (all positive ->
        //      raw float bits order like uints). cnt==1 early exit.
        const int nc = (int)sh_cnt;
        unsigned kmask = 0u;
        for (int q = 0; q < 4; ++q) {
            if (sh_cnt == 1u) break;         // block-uniform
            const int shift = 24 - 8 * q;
            hist[tid] = 0u;
            __syncthreads();
            const unsigned pref = sh_prefix;
            for (int i = tid; i < nc; i += BLOCK) {
                unsigned kk = candk[i];
                if ((kk & kmask) == pref) atomicAdd(&hist[(kk >> shift) & 0xFFu], 1u);
            }
            __syncthreads();
            if (tid < 64) scan_pick(hist, shift, tid, &sh_prefix, &sh_kr, &sh_cnt);
            kmask |= (0xFFu << shift);
            __syncthreads();
        }
        if (sh_cnt == 1u && kmask != 0xFFFFFFFFu) {
            const unsigned pref = sh_prefix;   // read before the single write
            __syncthreads();
            for (int i = tid; i < nc; i += BLOCK) {
                unsigned kk = candk[i];
                if ((kk & kmask) == pref) sh_prefix = kk;   // exactly one match
            }
            __syncthreads();
        }
        if (tid == 0) sh_thresh = __uint_as_float(sh_prefix);
    } else {
        // ---- Generic fallback (never hot): full-row radix on flipped keys
        for (int p = 0; p < 4; ++p) {
            const int shift = 24 - 8 * p;
            const unsigned pmask = p ? (0xFFFFFFFFu << (shift + 8)) : 0u;
            hist[tid] = 0u;
            __syncthreads();
            const unsigned pref = sh_prefix;
            for (int it = 0; it < NIT; ++it) {
                int j4 = it * BLOCK + tid;
                if (j4 < C4) {
                    float4 f = ((const float4*)lrow)[j4];
                    unsigned kk;
                    kk = flip_key(f.x); if ((kk & pmask) == pref) atomicAdd(&hist[(kk >> shift) & 0xFFu], 1u);
                    kk = flip_key(f.y); if ((kk & pmask) == pref) atomicAdd(&hist[(kk >> shift) & 0xFFu], 1u);
                    kk = flip_key(f.z); if ((kk & pmask) == pref) atomicAdd(&hist[(kk >> shift) & 0xFFu], 1u);
                    kk = flip_key(f.w); if ((kk & pmask) == pref) atomicAdd(&hist[(kk >> shift) & 0xFFu], 1u);
                }
            }
            __syncthreads();
            if (tid < 64) scan_pick(hist, shift, tid, &sh_prefix, &sh_kr, &sh_cnt);
            __syncthreads();
        }
        if (tid == 0) sh_thresh = unflip_key(sh_prefix);
    }
    __syncthreads();

    const float thresh = sh_thresh;
    const bool rare = fabsf(madjB) > 80.f;   // exp(adj) over/underflow guard

    // ---- Masked numerator sum
    float sm = 0.f;
    if (!rare) {
        if (path == 0) {
            // masked set is a subset of the candidates
            const int nc = (int)((sh_nc <= CAP) ? sh_nc : CAP);
            for (int i = tid; i < nc; i += BLOCK) {
                unsigned kk = candk[i];
                float v = __uint_as_float(kk);
                if (v >= thresh) sm += __expf(v + TAU * lcn[candi[i]]);
            }
        } else {
            for (int it = 0; it < NIT; ++it) {
                int j4 = it * BLOCK + tid;
                if (j4 < C4) {
                    float4 f = ((const float4*)lrow)[j4];
                    float4 l = ((const float4*)lcn)[j4];
                    if (f.x >= thresh) sm += __expf(f.x + TAU * l.x);
                    if (f.y >= thresh) sm += __expf(f.y + TAU * l.y);
                    if (f.z >= thresh) sm += __expf(f.z + TAU * l.z);
                    if (f.w >= thresh) sm += __expf(f.w + TAU * l.w);
                }
            }
        }
    } else {
        // exact re-sweep with max subtraction (never hot)
        z = 0.f;
        for (int it = 0; it < NIT; ++it) {
            int j4 = it * BLOCK + tid;
            if (j4 < C4) {
                float4 f = ((const float4*)lrow)[j4];
                float4 l = ((const float4*)lcn)[j4];
                float e;
                e = __expf(f.x + TAU * l.x - madjB); z += e; if (f.x >= thresh) sm += e;
                e = __expf(f.y + TAU * l.y - madjB); z += e; if (f.y >= thresh) sm += e;
                e = __expf(f.z + TAU * l.z - madjB); z += e; if (f.z >= thresh) sm += e;
                e = __expf(f.w + TAU * l.w - madjB); z += e; if (f.w >= thresh) sm += e;
            }
        }
    }

    // ---- Joint block reduction of z, sm
    for (int off = 32; off; off >>= 1) {
        z  += __shfl_down(z, off);
        sm += __shfl_down(sm, off);
    }
    if (lane == 0) { red_a[wid] = z; red_b[wid] = sm; }
    __syncthreads();

    if (tid == 0) {
        float Z = red_a[0] + red_a[1] + red_a[2] + red_a[3];
        float S = red_b[0] + red_b[1] + red_b[2] + red_b[3];
        int t = target[row];
        float logit_t = lrow[t];
        float adj_t = logit_t + TAU * lcn[t];
        float sub = rare ? madjB : 0.f;
        float lpt = adj_t - sub - __logf(Z);             // log_p_adj[target]
        float p_num = ((logit_t >= thresh) ? __expf(lpt) : 0.f) + 1e-6f;
        float Smask = S / Z + (float)C_DIM * 1e-6f;
        float loss = 0.5f * (-lpt + __logf(Smask) - __logf(p_num));
        atomicAdd(out, loss / (float)B);
    }
}

extern "C" void kernel_launch(void* const* d_in, const int* in_sizes, int n_in,
                              void* d_out, int out_size, void* d_ws, size_t ws_size,
                              hipStream_t stream) {
    const float* logit  = (const float*)d_in[0];
    const int*   target = (const int*)d_in[1];
    const float* lcn    = (const float*)d_in[2];
    const int*   kpc    = (const int*)d_in[3];
    float* out = (float*)d_out;
    const int B = in_sizes[1];   // target is [B]

    zero_out_kernel<<<1, 64, 0, stream>>>(out, out_size);
    topk_la_loss_kernel<<<B, BLOCK, 0, stream>>>(logit, target, lcn, kpc, out, B);
}